// Round 1
// baseline (66.515 us; speedup 1.0000x reference)
//
#include <hip/hip_runtime.h>
#include <math.h>

// GraphPoolMol: B=64, MAX_ATOM=128, N_FEAT=128
// out[b,i,f] = i<n ? max_{j<n, L[b,i,j]!=0} x[b,j,f]  (fallback x[b,i,f] if no nbr) : 0

#define MAX_ATOM 128
#define N_FEAT 128

__global__ __launch_bounds__(N_FEAT) void GraphPoolMol_kernel(
    const float* __restrict__ x,      // (B, MAX_ATOM, N_FEAT)
    const float* __restrict__ L,      // (B, MAX_ATOM, MAX_ATOM)
    const int* __restrict__ mol_slice,// (B, 2) -- col 0 = n_atoms
    float* __restrict__ out)          // (B, MAX_ATOM, N_FEAT)
{
    const int i = blockIdx.x;   // atom row
    const int b = blockIdx.y;   // batch
    const int f = threadIdx.x;  // feature index

    const int n = mol_slice[b * 2];

    const size_t base = ((size_t)b * MAX_ATOM + i) * N_FEAT;
    float* orow = out + base;

    if (i >= n) {
        orow[f] = 0.0f;
        return;
    }

    const float* __restrict__ xb   = x + (size_t)b * MAX_ATOM * N_FEAT;
    const float* __restrict__ Lrow = L + ((size_t)b * MAX_ATOM + i) * MAX_ATOM;

    __shared__ int nbr[MAX_ATOM];
    __shared__ int cnt;
    if (f == 0) cnt = 0;
    __syncthreads();

    // Each thread checks one column j = f of the laplacian row.
    float lv = (f < n) ? Lrow[f] : 0.0f;
    if (lv != 0.0f) {
        int pos = atomicAdd(&cnt, 1);
        nbr[pos] = f;
    }
    __syncthreads();

    const int m = cnt;
    float acc = -INFINITY;
    for (int k = 0; k < m; ++k) {
        const int j = nbr[k];               // broadcast read (no bank conflict)
        acc = fmaxf(acc, xb[(size_t)j * N_FEAT + f]);  // coalesced 512B row read
    }
    if (m == 0) acc = xb[(size_t)i * N_FEAT + f];  // no-neighbor fallback
    orow[f] = acc;
}

extern "C" void kernel_launch(void* const* d_in, const int* in_sizes, int n_in,
                              void* d_out, int out_size, void* d_ws, size_t ws_size,
                              hipStream_t stream) {
    const float* x   = (const float*)d_in[0];   // node_features (64,128,128) f32
    const float* L   = (const float*)d_in[1];   // laplacian     (64,128,128) f32
    const int* mol   = (const int*)d_in[2];     // mol_slice     (64,2) i32
    // d_in[3] = l_slice (unused)
    float* out = (float*)d_out;

    dim3 grid(MAX_ATOM, 64);
    dim3 block(N_FEAT);
    GraphPoolMol_kernel<<<grid, block, 0, stream>>>(x, L, mol, out);
}